// Round 12
// baseline (47.281 us; speedup 1.0000x reference)
//
#include <hip/hip_runtime.h>
#include <stdint.h>

#define BATCH 64
#define NPS (512*512)                 // 262144 elements per sample
#define THREADS 256
#define BPS 32                        // blocks per sample
#define NBLOCKS (BATCH*BPS)           // 2048 blocks = 8/CU
#define EPB (NPS/BPS)                 // 8192 elements per block
#define V4 (EPB/(THREADS*4))          // 8 float4 iterations per thread
#define NBINS 512                     // sigmoid-space bins

// ws layout: Cnt2 u32[NBLOCKS][NBINS] (4 MiB) | Scal
#define CNT2_BYTES (NBLOCKS*NBINS*sizeof(uint32_t))

typedef float fvec4 __attribute__((ext_vector_type(4)));

struct Scal {
  float bce[BATCH];
  float ps[BATCH];     // per-sample sigma(p)
  float inter[BATCH];  // per-sample sigma(p*t)
  float tsum[BATCH];   // per-sample sigma(t) == ones (exact: < 2^24)
  float Ssm[BATCH];    // approx S_small
  uint32_t done;       // last-block ticket (zeroed by memset each launch)
};

// ---- fused pass: BCE/Dice sums + per-sample sigmoid-space count hist ----
__global__ __launch_bounds__(THREADS, 4) void k_main(
    const float* __restrict__ x, const float* __restrict__ t,
    uint32_t* __restrict__ Cnt2, Scal* __restrict__ sc)
{
  int s = blockIdx.x / BPS;
  int chunk = blockIdx.x % BPS;
  __shared__ uint32_t hc[NBINS];
  for (int i = threadIdx.x; i < NBINS; i += THREADS) hc[i] = 0u;
  __syncthreads();

  size_t base = (size_t)s*NPS + (size_t)chunk*EPB;
  const fvec4* __restrict__ xp = (const fvec4*)(x + base) + threadIdx.x;
  const fvec4* __restrict__ tp = (const fvec4*)(t + base) + threadIdx.x;

  float bce=0.f, ps=0.f, inter=0.f, tsf=0.f;

#define EL(xx, tt) {                                        \
    float e  = __expf(-fabsf(xx));                          \
    float u  = 1.f + e;                                     \
    float lg = __logf(u);                                   \
    float r  = __builtin_amdgcn_rcpf(u);  /* sigmoid(|x|) */\
    float p  = (xx >= 0.f) ? r : 1.f - r;                   \
    float xs = (tt > 0.5f) ? -xx : xx;                      \
    bce  += fmaxf(xs, 0.f) + lg;                            \
    ps   += p;                                              \
    inter = fmaf(p, tt, inter);                             \
    tsf  += tt;                                             \
    int bin = (int)(p * (float)NBINS);                      \
    bin = (bin > NBINS-1) ? (NBINS-1) : bin;                \
    atomicAdd(&hc[bin], 1u);                                \
  }
#define P4(XV, TV) { EL(XV.x, TV.x) EL(XV.y, TV.y) EL(XV.z, TV.z) EL(XV.w, TV.w) }

  // distance-2 rotating software pipeline, non-temporal loads
  fvec4 cx0 = __builtin_nontemporal_load(xp + 0*THREADS);
  fvec4 ct0 = __builtin_nontemporal_load(tp + 0*THREADS);
  fvec4 cx1 = __builtin_nontemporal_load(xp + 1*THREADS);
  fvec4 ct1 = __builtin_nontemporal_load(tp + 1*THREADS);
  #pragma unroll
  for (int it = 0; it < V4; ++it){
    fvec4 nx, nt;
    if (it + 2 < V4){
      nx = __builtin_nontemporal_load(xp + (it+2)*THREADS);
      nt = __builtin_nontemporal_load(tp + (it+2)*THREADS);
    }
    P4(cx0, ct0)
    cx0 = cx1; ct0 = ct1;
    cx1 = nx;  ct1 = nt;
  }
#undef P4
#undef EL

  // block-reduce scalar sums
  #pragma unroll
  for (int o=32;o>0;o>>=1){
    bce += __shfl_down(bce,o); ps += __shfl_down(ps,o);
    inter += __shfl_down(inter,o); tsf += __shfl_down(tsf,o);
  }
  __shared__ float rb[4], rp[4], ri[4], rt[4];
  int wave = threadIdx.x >> 6, lane = threadIdx.x & 63;
  if (lane==0){ rb[wave]=bce; rp[wave]=ps; ri[wave]=inter; rt[wave]=tsf; }
  __syncthreads();
  if (threadIdx.x==0){
    atomicAdd(&sc->bce[s],   rb[0]+rb[1]+rb[2]+rb[3]);
    atomicAdd(&sc->ps[s],    rp[0]+rp[1]+rp[2]+rp[3]);
    atomicAdd(&sc->inter[s], ri[0]+ri[1]+ri[2]+ri[3]);
    atomicAdd(&sc->tsum[s],  rt[0]+rt[1]+rt[2]+rt[3]);
  }
  __syncthreads();
  // contention-free flush: plain coalesced stores to private slice
  uint32_t* dst = Cnt2 + (size_t)blockIdx.x * NBINS;
  for (int i = threadIdx.x; i < NBINS; i += THREADS) dst[i] = hc[i];
}

// ---- per-sample select + (last block) final combine ----------------------
__global__ __launch_bounds__(THREADS) void k_fin(
    const uint32_t* __restrict__ Cnt2, Scal* __restrict__ sc, float* __restrict__ out)
{
  int s = blockIdx.x;
  uint32_t ones = (uint32_t)(sc->tsum[s] + 0.5f);
  uint32_t z = (uint32_t)NPS - ones;

  __shared__ uint32_t pre[THREADS];
  __shared__ int sB; __shared__ uint32_t sr;
  __shared__ uint32_t sticket;
  if (threadIdx.x==0){ sB = 0; sr = 0u; }

  // sum the 32 per-block slices: thread owns bins {2t, 2t+1}
  uint32_t h0 = 0u, h1 = 0u;
  const uint32_t* basep = Cnt2 + (size_t)s * BPS * NBINS + 2u*threadIdx.x;
  #pragma unroll 8
  for (int c = 0; c < BPS; ++c){
    uint2 v = *(const uint2*)(basep + (size_t)c * NBINS);
    h0 += v.x; h1 += v.y;
  }
  uint32_t local = h0 + h1;
  pre[threadIdx.x] = local;
  __syncthreads();
  if (threadIdx.x==0){ uint32_t c=0; for(int i=0;i<THREADS;i++){uint32_t v=pre[i]; pre[i]=c; c+=v;} }
  __syncthreads();
  uint32_t before = pre[threadIdx.x];
  if (z != 0u && before < z && z <= before+local){
    if (z <= before + h0){ sB = 2*threadIdx.x;   sr = z - before; }
    else                 { sB = 2*threadIdx.x+1; sr = z - before - h0; }
  }
  __syncthreads();
  int B = sB; uint32_t r = sr;

  // S_small ~= [ sum_{b<B} h[b]*(b+.5) + r*(B+.5) ] / NBINS
  float acc = 0.f;
  if (2*threadIdx.x   < B) acc += (float)h0 * ((float)(2*threadIdx.x)  +0.5f);
  if (2*threadIdx.x+1 < B) acc += (float)h1 * ((float)(2*threadIdx.x+1)+0.5f);
  #pragma unroll
  for (int o=32;o>0;o>>=1) acc += __shfl_down(acc,o);
  __shared__ float rs[4];
  int wave=threadIdx.x>>6, lane=threadIdx.x&63;
  if (lane==0) rs[wave]=acc;
  __syncthreads();

  // publish Ssm[s], then last block runs the 1-wave final combine
  if (threadIdx.x==0){
    float below = rs[0]+rs[1]+rs[2]+rs[3] + (float)r * ((float)B + 0.5f);
    sc->Ssm[s] = (z==0u) ? 0.f : below * (1.0f/(float)NBINS);
    __threadfence();                       // release Ssm before ticket
    sticket = atomicAdd(&sc->done, 1u);    // device-scope
  }
  __syncthreads();
  if (sticket == (uint32_t)(BATCH-1)){
    __threadfence();                       // acquire other blocks' writes
    if (threadIdx.x < 64){
      int b = threadIdx.x;
      float Stot = sc->ps[b];
      float onef = sc->tsum[b];
      float tp   = (2.f*sc->Ssm[b] - Stot + onef) * (1.0f/(float)NPS);
      float bce  = sc->bce[b];
      float inter= sc->inter[b];
      float psum = Stot;
      #pragma unroll
      for (int o=32;o>0;o>>=1){
        tp   += __shfl_down(tp,o);   bce  += __shfl_down(bce,o);
        psum += __shfl_down(psum,o); inter+= __shfl_down(inter,o);
        onef += __shfl_down(onef,o);
      }
      if (b==0){
        float mbce = bce / ((float)BATCH*(float)NPS);
        float dice = 1.f - (2.f*inter + 1e-6f)/(psum + onef + 1e-6f);
        out[0] = 0.5f*mbce + 1.0f*dice + 0.5f*tp;
      }
    }
  }
}

extern "C" void kernel_launch(void* const* d_in, const int* in_sizes, int n_in,
                              void* d_out, int out_size, void* d_ws, size_t ws_size,
                              hipStream_t stream){
  const float* x = (const float*)d_in[0];
  const float* t = (const float*)d_in[1];
  float* out = (float*)d_out;
  uint8_t* ws = (uint8_t*)d_ws;
  uint32_t* Cnt2 = (uint32_t*)ws;
  Scal* sc = (Scal*)(ws + CNT2_BYTES);

  hipMemsetAsync(sc, 0, sizeof(Scal), stream);   // zeroes sums + done ticket
  k_main<<<NBLOCKS, THREADS, 0, stream>>>(x, t, Cnt2, sc);
  k_fin<<<BATCH, THREADS, 0, stream>>>(Cnt2, sc, out);
}

// Round 13
// 43.420 us; speedup vs baseline: 1.0889x; 1.0889x over previous
//
#include <hip/hip_runtime.h>
#include <stdint.h>

#define BATCH 64
#define NPS (512*512)                 // 262144 elements per sample
#define THREADS 256
#define BPS 32                        // blocks per sample
#define NBLOCKS (BATCH*BPS)           // 2048 blocks = 8/CU
#define EPB (NPS/BPS)                 // 8192 elements per block
#define V4 (EPB/(THREADS*4))          // 8 float4 iterations per thread
#define NBINS 512                     // sigmoid-space bins

// ws layout: Cnt2 u32[NBLOCKS][NBINS] (4 MiB) | Scal
#define CNT2_BYTES (NBLOCKS*NBINS*sizeof(uint32_t))

typedef float fvec4 __attribute__((ext_vector_type(4)));

struct Scal {
  float bce[BATCH];
  float ps[BATCH];     // per-sample sigma(p)
  float inter[BATCH];  // per-sample sigma(p*t)
  float tsum[BATCH];   // per-sample sigma(t) == ones (exact: < 2^24)
  float Ssm[BATCH];    // approx S_small
};

// ---- fused pass: BCE/Dice sums + per-sample sigmoid-space count hist ----
__global__ __launch_bounds__(THREADS, 4) void k_main(
    const float* __restrict__ x, const float* __restrict__ t,
    uint32_t* __restrict__ Cnt2, Scal* __restrict__ sc)
{
  int s = blockIdx.x / BPS;
  int chunk = blockIdx.x % BPS;
  __shared__ uint32_t hc[NBINS];
  for (int i = threadIdx.x; i < NBINS; i += THREADS) hc[i] = 0u;
  __syncthreads();

  size_t base = (size_t)s*NPS + (size_t)chunk*EPB;
  const fvec4* __restrict__ xp = (const fvec4*)(x + base) + threadIdx.x;
  const fvec4* __restrict__ tp = (const fvec4*)(t + base) + threadIdx.x;

  float bce=0.f, ps=0.f, inter=0.f, tsf=0.f;

#define EL(xx, tt) {                                        \
    float e  = __expf(-fabsf(xx));                          \
    float u  = 1.f + e;                                     \
    float lg = __logf(u);                                   \
    float r  = __builtin_amdgcn_rcpf(u);  /* sigmoid(|x|) */\
    float p  = (xx >= 0.f) ? r : 1.f - r;                   \
    float xs = (tt > 0.5f) ? -xx : xx;                      \
    bce  += fmaxf(xs, 0.f) + lg;                            \
    ps   += p;                                              \
    inter = fmaf(p, tt, inter);                             \
    tsf  += tt;                                             \
    int bin = (int)(p * (float)NBINS);                      \
    bin = (bin > NBINS-1) ? (NBINS-1) : bin;                \
    atomicAdd(&hc[bin], 1u);                                \
  }
#define P4(XV, TV) { EL(XV.x, TV.x) EL(XV.y, TV.y) EL(XV.z, TV.z) EL(XV.w, TV.w) }

  // distance-2 rotating software pipeline, non-temporal loads (pure HBM stream)
  fvec4 cx0 = __builtin_nontemporal_load(xp + 0*THREADS);
  fvec4 ct0 = __builtin_nontemporal_load(tp + 0*THREADS);
  fvec4 cx1 = __builtin_nontemporal_load(xp + 1*THREADS);
  fvec4 ct1 = __builtin_nontemporal_load(tp + 1*THREADS);
  #pragma unroll
  for (int it = 0; it < V4; ++it){
    fvec4 nx, nt;
    if (it + 2 < V4){
      nx = __builtin_nontemporal_load(xp + (it+2)*THREADS);
      nt = __builtin_nontemporal_load(tp + (it+2)*THREADS);
    }
    P4(cx0, ct0)
    cx0 = cx1; ct0 = ct1;
    cx1 = nx;  ct1 = nt;
  }
#undef P4
#undef EL

  // block-reduce scalar sums
  #pragma unroll
  for (int o=32;o>0;o>>=1){
    bce += __shfl_down(bce,o); ps += __shfl_down(ps,o);
    inter += __shfl_down(inter,o); tsf += __shfl_down(tsf,o);
  }
  __shared__ float rb[4], rp[4], ri[4], rt[4];
  int wave = threadIdx.x >> 6, lane = threadIdx.x & 63;
  if (lane==0){ rb[wave]=bce; rp[wave]=ps; ri[wave]=inter; rt[wave]=tsf; }
  __syncthreads();
  if (threadIdx.x==0){
    atomicAdd(&sc->bce[s],   rb[0]+rb[1]+rb[2]+rb[3]);
    atomicAdd(&sc->ps[s],    rp[0]+rp[1]+rp[2]+rp[3]);
    atomicAdd(&sc->inter[s], ri[0]+ri[1]+ri[2]+ri[3]);
    atomicAdd(&sc->tsum[s],  rt[0]+rt[1]+rt[2]+rt[3]);
  }
  __syncthreads();
  // contention-free flush: plain coalesced stores to private slice
  uint32_t* dst = Cnt2 + (size_t)blockIdx.x * NBINS;
  for (int i = threadIdx.x; i < NBINS; i += THREADS) dst[i] = hc[i];
}

// ---- per-sample: sum slices, find threshold bin, approx S_small ---------
__global__ __launch_bounds__(THREADS) void k_fin(
    const uint32_t* __restrict__ Cnt2, Scal* __restrict__ sc)
{
  int s = blockIdx.x;
  uint32_t ones = (uint32_t)(sc->tsum[s] + 0.5f);
  uint32_t z = (uint32_t)NPS - ones;
  if (z == 0u){ if (threadIdx.x==0) sc->Ssm[s] = 0.f; return; }

  __shared__ uint32_t pre[THREADS];
  __shared__ int sB; __shared__ uint32_t sr;

  // sum the 32 per-block slices: thread owns bins {2t, 2t+1}
  uint32_t h0 = 0u, h1 = 0u;
  const uint32_t* basep = Cnt2 + (size_t)s * BPS * NBINS + 2u*threadIdx.x;
  #pragma unroll 8
  for (int c = 0; c < BPS; ++c){
    uint2 v = *(const uint2*)(basep + (size_t)c * NBINS);
    h0 += v.x; h1 += v.y;
  }
  uint32_t local = h0 + h1;
  pre[threadIdx.x] = local;
  __syncthreads();
  if (threadIdx.x==0){ uint32_t c=0; for(int i=0;i<THREADS;i++){uint32_t v=pre[i]; pre[i]=c; c+=v;} }
  __syncthreads();
  uint32_t before = pre[threadIdx.x];
  if (before < z && z <= before+local){
    if (z <= before + h0){ sB = 2*threadIdx.x;   sr = z - before; }
    else                 { sB = 2*threadIdx.x+1; sr = z - before - h0; }
  }
  __syncthreads();
  int B = sB; uint32_t r = sr;

  // S_small ~= [ sum_{b<B} h[b]*(b+.5) + r*(B+.5) ] / NBINS
  float acc = 0.f;
  if (2*threadIdx.x   < B) acc += (float)h0 * ((float)(2*threadIdx.x)  +0.5f);
  if (2*threadIdx.x+1 < B) acc += (float)h1 * ((float)(2*threadIdx.x+1)+0.5f);
  #pragma unroll
  for (int o=32;o>0;o>>=1) acc += __shfl_down(acc,o);
  __shared__ float rs[4];
  int wave=threadIdx.x>>6, lane=threadIdx.x&63;
  if (lane==0) rs[wave]=acc;
  __syncthreads();
  if (threadIdx.x==0){
    float below = rs[0]+rs[1]+rs[2]+rs[3] + (float)r * ((float)B + 0.5f);
    sc->Ssm[s] = below * (1.0f/(float)NBINS);
  }
}

// ---- final combine (one wave) --------------------------------------------
__global__ void k_final(const Scal* __restrict__ sc, float* __restrict__ out){
  int b = threadIdx.x; // 64 lanes = 64 samples
  float Stot = sc->ps[b];
  float onef = sc->tsum[b];
  float tp   = (2.f*sc->Ssm[b] - Stot + onef) * (1.0f/(float)NPS);
  float bce  = sc->bce[b];
  float inter= sc->inter[b];
  float psum = Stot;
  #pragma unroll
  for (int o=32;o>0;o>>=1){
    tp   += __shfl_down(tp,o);   bce  += __shfl_down(bce,o);
    psum += __shfl_down(psum,o); inter+= __shfl_down(inter,o);
    onef += __shfl_down(onef,o);
  }
  if (b==0){
    float mbce = bce / ((float)BATCH*(float)NPS);
    float dice = 1.f - (2.f*inter + 1e-6f)/(psum + onef + 1e-6f);
    out[0] = 0.5f*mbce + 1.0f*dice + 0.5f*tp;
  }
}

extern "C" void kernel_launch(void* const* d_in, const int* in_sizes, int n_in,
                              void* d_out, int out_size, void* d_ws, size_t ws_size,
                              hipStream_t stream){
  const float* x = (const float*)d_in[0];
  const float* t = (const float*)d_in[1];
  float* out = (float*)d_out;
  uint8_t* ws = (uint8_t*)d_ws;
  uint32_t* Cnt2 = (uint32_t*)ws;
  Scal* sc = (Scal*)(ws + CNT2_BYTES);

  hipMemsetAsync(sc, 0, sizeof(Scal), stream);   // Cnt2 fully overwritten, no memset
  k_main<<<NBLOCKS, THREADS, 0, stream>>>(x, t, Cnt2, sc);
  k_fin<<<BATCH, THREADS, 0, stream>>>(Cnt2, sc);
  k_final<<<1, 64, 0, stream>>>(sc, out);
}